// Round 5
// baseline (238.837 us; speedup 1.0000x reference)
//
#include <hip/hip_runtime.h>
#include <cstddef>
#include <math.h>

// Numerics are frozen to round-4's numpy-f32 mimicry (absmax margin is thin:
// 0.0156 vs 0.02). This version changes ONLY data movement / thread mapping:
//   - coalesced global->LDS staging (was: 64 lanes reading rows 4KB apart)
//   - bucket sums per-thread sequential from LDS (bit-identical order)
//   - parallel input softmaxes (256 tasks) and output double-softmaxes (128)
//   - serial carry chain (verbatim einsum + carry softmax2) on 64 threads
//   - coalesced outer-product stores
// Every f32 op and its order is identical to the passing kernel.

__device__ __forceinline__ float exf(float t) {
  return (float)exp((double)t);  // correctly-rounded f32 exp (matches np closely)
}

// softmax(x*100) with numpy rounding/order.
__device__ __forceinline__ void softmax16_np(const float* x, float* p) {
#pragma clang fp contract(off)
  float t[16];
#pragma unroll
  for (int j = 0; j < 16; ++j) t[j] = x[j] * 100.0f;  // scale FIRST (rounded)
  float m = t[0];
#pragma unroll
  for (int j = 1; j < 16; ++j) m = fmaxf(m, t[j]);
  float e[16];
#pragma unroll
  for (int j = 0; j < 16; ++j) e[j] = exf(t[j] - m);
  // numpy pairwise sum, n=16
  float r0 = e[0] + e[8], r1 = e[1] + e[9], r2 = e[2] + e[10], r3 = e[3] + e[11];
  float r4 = e[4] + e[12], r5 = e[5] + e[13], r6 = e[6] + e[14], r7 = e[7] + e[15];
  float s = ((r0 + r1) + (r2 + r3)) + ((r4 + r5) + (r6 + r7));
#pragma unroll
  for (int j = 0; j < 16; ++j) p[j] = e[j] / s;  // true division
}

// Serial part of the soft nibble add: raw sums s[16] (pre-softmax) + carry
// probs (n0,n1). Accumulation order verbatim from the passing kernel.
__device__ __forceinline__ void nibble_add_raw(const float* px, const float* py,
                                               float c0, float c1,
                                               float* s, float& n0, float& n1) {
#pragma clang fp contract(off)
  float ca = 0.f, cb = 0.f;
#pragma unroll
  for (int l = 0; l < 16; ++l) s[l] = 0.f;
#pragma unroll
  for (int i = 0; i < 16; ++i) {
#pragma unroll
    for (int j = 0; j < 16; ++j) {
      float wij = px[i] * py[j];
      float w0 = wij * c0;
      float w1 = wij * c1;
      const int t0 = i + j, t1 = i + j + 1;
      s[t0 & 15] += w0;
      if (t0 < 16) ca += w0; else cb += w0;
      s[t1 & 15] += w1;
      if (t1 < 16) ca += w1; else cb += w1;
    }
  }
  float u0 = ca * 100.0f, u1 = cb * 100.0f;
  float m = fmaxf(u0, u1);
  float e0 = exf(u0 - m), e1 = exf(u1 - m);
  float ss = e0 + e1;
  n0 = e0 / ss;
  n1 = e1 / ss;
}

// Block: 256 threads, 64 batches. Assumes nbatch % 64 == 0 (B=32768).
extern "C" __global__ void __launch_bounds__(256, 2)
byteadd_kernel(const float* __restrict__ A, const float* __restrict__ Bm,
               float* __restrict__ O, int nbatch) {
  __shared__ float buf[32][260];   // staged 32-batch byte-slice (33.3 KB)
  __shared__ float comb[64][67];   // a_hi 0..15 | a_lo 16..31 | b_hi 34..49 | b_lo 50..65
  __shared__ float pout[64][36];   // sh/ph2 0..15 | sl/pl2 20..35

  const int tid = threadIdx.x;
  const int batch0 = blockIdx.x * 64;
  if (batch0 >= nbatch) return;

  // Reference quirk: initial carry [1.0] broadcasts to BOTH carry slots.
  float cr0 = 1.0f, cr1 = 1.0f;  // live in threads tid<64

#pragma unroll 1
  for (int i = 0; i < 4; ++i) {
    // ---------------- Phase A: buckets for both inputs via LDS ----------------
    for (int inp = 0; inp < 2; ++inp) {
      const float* __restrict__ src = (inp == 0) ? A : Bm;
      for (int h = 0; h < 2; ++h) {
        __syncthreads();  // buf free (previous consumers done)
#pragma unroll
        for (int r = 0; r < 8; ++r) {          // coalesced: each wave reads 1KB runs
          int row = r * 4 + (tid >> 6);        // 0..31
          int c4 = tid & 63;
          const float* p = src + ((size_t)(batch0 + h * 32 + row) * 1024 + i * 256 + c4 * 4);
          *(float4*)&buf[row][c4 * 4] = *(const float4*)p;
        }
        __syncthreads();
        // 32 batches x 32 buckets, 4 buckets/thread, sequential ascending order
        {
#pragma clang fp contract(off)
          int bb = tid >> 3;   // 0..31
          int g = tid & 7;     // 0..7
          float acc[4] = {0.f, 0.f, 0.f, 0.f};
          if (g < 4) {
            // hi buckets u = 4g+u4: elements 16u..16u+15 (contiguous)
#pragma unroll
            for (int u4 = 0; u4 < 4; ++u4)
#pragma unroll
              for (int k4 = 0; k4 < 4; ++k4) {
                float4 v = *(const float4*)&buf[bb][g * 64 + u4 * 16 + k4 * 4];
                acc[u4] += v.x; acc[u4] += v.y; acc[u4] += v.z; acc[u4] += v.w;
              }
#pragma unroll
            for (int u4 = 0; u4 < 4; ++u4)
              comb[h * 32 + bb][inp * 34 + g * 4 + u4] = acc[u4];
          } else {
            // lo buckets l = 4(g-4)+q: elements l, l+16, ..., l+240 (ascending)
            int l0 = (g - 4) * 4;
#pragma unroll
            for (int k = 0; k < 16; ++k) {
              float4 v = *(const float4*)&buf[bb][l0 + k * 16];
              acc[0] += v.x; acc[1] += v.y; acc[2] += v.z; acc[3] += v.w;
            }
#pragma unroll
            for (int q = 0; q < 4; ++q)
              comb[h * 32 + bb][inp * 34 + 16 + l0 + q] = acc[q];
          }
        }
      }
    }
    __syncthreads();

    // ------------- input softmaxes: 64 batches x 4 = 256 tasks -------------
    {
      int bb = tid >> 2, w = tid & 3;
      int off = (w >> 1) * 34 + (w & 1) * 16;
      float x[16], p[16];
#pragma unroll
      for (int j = 0; j < 16; ++j) x[j] = comb[bb][off + j];
      softmax16_np(x, p);
#pragma unroll
      for (int j = 0; j < 16; ++j) comb[bb][off + j] = p[j];
    }
    __syncthreads();

    // ------------- serial carry chain: one batch per thread (tid<64) -------------
    if (tid < 64) {
      float pxl[16], pyl[16];
#pragma unroll
      for (int j = 0; j < 16; ++j) { pxl[j] = comb[tid][16 + j]; pyl[j] = comb[tid][50 + j]; }
      float sl[16], d0, d1;
      nibble_add_raw(pxl, pyl, cr0, cr1, sl, d0, d1);   // low add, carry in
#pragma unroll
      for (int j = 0; j < 16; ++j) pout[tid][20 + j] = sl[j];
      float pxh[16], pyh[16];
#pragma unroll
      for (int j = 0; j < 16; ++j) { pxh[j] = comb[tid][j]; pyh[j] = comb[tid][34 + j]; }
      float sh[16];
      nibble_add_raw(pxh, pyh, d0, d1, sh, cr0, cr1);   // high add, carry -> next byte
#pragma unroll
      for (int j = 0; j < 16; ++j) pout[tid][j] = sh[j];
    }
    __syncthreads();

    // ------- output double-softmax: 64 batches x 2 nibbles = 128 tasks -------
    if (tid < 128) {
      int bb = tid >> 1;
      int off = (tid & 1) * 20;
      float x[16], p[16], p2[16];
#pragma unroll
      for (int j = 0; j < 16; ++j) x[j] = pout[bb][off + j];
      softmax16_np(x, p);    // ps (nibble_add's output softmax)
      softmax16_np(p, p2);   // from_nibbles softmax (separable factor)
#pragma unroll
      for (int j = 0; j < 16; ++j) pout[bb][off + j] = p2[j];
    }
    __syncthreads();

    // ------------- outer-product expansion, coalesced stores -------------
#pragma unroll
    for (int kk = 0; kk < 16; ++kk) {
      int flat = kk * 1024 + tid * 4;   // 64 batches x 256 bytes
      int bb = flat >> 8;
      int b0 = flat & 255;              // multiple of 4
      float ph = pout[bb][b0 >> 4];
      int lo = 20 + (b0 & 15);
      float4 o;
      o.x = ph * pout[bb][lo + 0];
      o.y = ph * pout[bb][lo + 1];
      o.z = ph * pout[bb][lo + 2];
      o.w = ph * pout[bb][lo + 3];
      *(float4*)(O + ((size_t)(batch0 + bb) * 4 + i) * 256 + b0) = o;
    }
  }
}

extern "C" void kernel_launch(void* const* d_in, const int* in_sizes, int n_in,
                              void* d_out, int out_size, void* d_ws, size_t ws_size,
                              hipStream_t stream) {
  const float* A = (const float*)d_in[0];
  const float* B = (const float*)d_in[1];
  float* O = (float*)d_out;
  int nbatch = in_sizes[0] / 1024;          // [B,4,256] -> B
  int blocks = (nbatch + 63) / 64;          // B=32768 -> 512 blocks
  byteadd_kernel<<<dim3(blocks), dim3(256), 0, stream>>>(A, B, O, nbatch);
}

// Round 6
// 197.115 us; speedup vs baseline: 1.2117x; 1.2117x over previous
//
#include <hip/hip_runtime.h>
#include <cstddef>
#include <math.h>

// 3-kernel pipeline. Numerics are FROZEN to the passing R4/R5 recipe
// (absmax 0.015625 vs threshold 0.02): numpy-f32 op ordering everywhere —
// ascending bucket sums, scale-first softmax with pairwise-16 sum and true
// division, (i,j,k)-lex einsum with materialized w rounding, f64-exact exp.
// Only data movement / thread mapping changes.
//   K1: inputs -> bucket sums -> input softmaxes -> ws1 probs   [parallel]
//   K2: serial per-batch carry chain (einsum + carry softmax2)  [512 waves]
//   K3: double output softmax + outer-product expansion -> O    [parallel]

__device__ __forceinline__ float exf(float t) {
  return (float)exp((double)t);  // correctly-rounded f32 exp
}

// softmax(x*100) with numpy rounding/order.
__device__ __forceinline__ void softmax16_np(const float* x, float* p) {
#pragma clang fp contract(off)
  float t[16];
#pragma unroll
  for (int j = 0; j < 16; ++j) t[j] = x[j] * 100.0f;  // scale FIRST (rounded)
  float m = t[0];
#pragma unroll
  for (int j = 1; j < 16; ++j) m = fmaxf(m, t[j]);
  float e[16];
#pragma unroll
  for (int j = 0; j < 16; ++j) e[j] = exf(t[j] - m);
  float r0 = e[0] + e[8], r1 = e[1] + e[9], r2 = e[2] + e[10], r3 = e[3] + e[11];
  float r4 = e[4] + e[12], r5 = e[5] + e[13], r6 = e[6] + e[14], r7 = e[7] + e[15];
  float s = ((r0 + r1) + (r2 + r3)) + ((r4 + r5) + (r6 + r7));
#pragma unroll
  for (int j = 0; j < 16; ++j) p[j] = e[j] / s;  // true division
}

// Serial soft nibble add: raw sums s[16] (pre-softmax) + carry probs (n0,n1).
// Accumulation order verbatim from the passing kernel.
__device__ __forceinline__ void nibble_add_raw(const float* px, const float* py,
                                               float c0, float c1,
                                               float* s, float& n0, float& n1) {
#pragma clang fp contract(off)
  float ca = 0.f, cb = 0.f;
#pragma unroll
  for (int l = 0; l < 16; ++l) s[l] = 0.f;
#pragma unroll
  for (int i = 0; i < 16; ++i) {
#pragma unroll
    for (int j = 0; j < 16; ++j) {
      float wij = px[i] * py[j];
      float w0 = wij * c0;
      float w1 = wij * c1;
      const int t0 = i + j, t1 = i + j + 1;
      s[t0 & 15] += w0;
      if (t0 < 16) ca += w0; else cb += w0;
      s[t1 & 15] += w1;
      if (t1 < 16) ca += w1; else cb += w1;
    }
  }
  float u0 = ca * 100.0f, u1 = cb * 100.0f;
  float m = fmaxf(u0, u1);
  float e0 = exf(u0 - m), e1 = exf(u1 - m);
  float ss = e0 + e1;
  n0 = e0 / ss;
  n1 = e1 / ss;
}

// ---------------- K1: buckets + input softmax -> ws1 ----------------
// ws1 row r = (ib*2+inp)*32 + nib*16 + j  (256 rows x nbatch, batch-major)
extern "C" __global__ void __launch_bounds__(256, 1)
k1_prep(const float* __restrict__ A, const float* __restrict__ Bm,
        float* __restrict__ ws1, int nbatch) {
  __shared__ float buf[32][257];   // +1 pad: stride%32==1
  __shared__ float comb[32][33];
  const int tid = threadIdx.x;
  const int batch0 = blockIdx.x * 32;
  const int ib = blockIdx.y;
  const int inp = blockIdx.z;
  if (batch0 >= nbatch) return;
  const float* __restrict__ src =
      (inp == 0 ? A : Bm) + (size_t)batch0 * 1024 + ib * 256;

  // stage 32 batches x 256 floats; each wave reads whole 1KB rows
#pragma unroll
  for (int r = 0; r < 8; ++r) {
    int idx = r * 256 + tid;          // float4 index
    int row = idx >> 6, c4 = idx & 63;
    *(float4*)&buf[row][c4 * 4] = *(const float4*)(src + (size_t)row * 1024 + c4 * 4);
  }
  __syncthreads();

  // bucket sums: thread (g=tid>>5, bb=tid&31) -> 4 buckets, ascending order.
  // g is wave-uniform (2 g-values per wave) -> no divergence, 2-way LDS alias.
  {
#pragma clang fp contract(off)
    const int g = tid >> 5, bb = tid & 31;
    float acc[4] = {0.f, 0.f, 0.f, 0.f};
    if (g < 4) {
      // hi buckets u = 4g+q: elements 16u..16u+15 (contiguous, ascending)
#pragma unroll
      for (int q = 0; q < 4; ++q) {
        float a = 0.f;
#pragma unroll
        for (int k4 = 0; k4 < 4; ++k4) {
          float4 v = *(const float4*)&buf[bb][(g * 4 + q) * 16 + k4 * 4];
          a += v.x; a += v.y; a += v.z; a += v.w;
        }
        acc[q] = a;
      }
#pragma unroll
      for (int q = 0; q < 4; ++q) comb[bb][g * 4 + q] = acc[q];
    } else {
      // lo buckets l = 4(g-4)+q: elements l+16m, m ascending
      const int l0 = (g - 4) * 4;
#pragma unroll
      for (int m = 0; m < 16; ++m) {
        float4 v = *(const float4*)&buf[bb][m * 16 + l0];
        acc[0] += v.x; acc[1] += v.y; acc[2] += v.z; acc[3] += v.w;
      }
#pragma unroll
      for (int q = 0; q < 4; ++q) comb[bb][16 + l0 + q] = acc[q];
    }
  }
  __syncthreads();

  // input softmaxes: 32 batches x 2 nibbles = 64 tasks
  if (tid < 64) {
    const int nib = tid >> 5, bb = tid & 31;
    float x[16], p[16];
#pragma unroll
    for (int j = 0; j < 16; ++j) x[j] = comb[bb][nib * 16 + j];
    softmax16_np(x, p);
    const size_t r0 = (size_t)((ib * 2 + inp) * 32 + nib * 16);
#pragma unroll
    for (int j = 0; j < 16; ++j)
      ws1[(r0 + j) * nbatch + batch0 + bb] = p[j];
  }
}

// ---------------- K2: serial carry chain -> ws2 ----------------
// reads ws1 rows i*64 + t (t = inp*32+nib*16+j); writes ws2 rows i*32 + nib*16 + l
__device__ __forceinline__ void k2_load(const float* __restrict__ ws1, int i,
                                        size_t batch, int nbatch, float* b) {
#pragma unroll
  for (int t = 0; t < 64; ++t)
    b[t] = ws1[(size_t)(i * 64 + t) * nbatch + batch];
}

__device__ __forceinline__ void k2_step(const float* b, float& cr0, float& cr1,
                                        float* __restrict__ ws2, int i,
                                        size_t batch, int nbatch) {
  float sl[16], sh[16], d0, d1;
  nibble_add_raw(b + 16, b + 48, cr0, cr1, sl, d0, d1);   // low add, carry in
  nibble_add_raw(b + 0,  b + 32, d0, d1, sh, cr0, cr1);   // high add, carry out
#pragma unroll
  for (int l = 0; l < 16; ++l) {
    ws2[(size_t)(i * 32 + l) * nbatch + batch] = sh[l];        // nib 0 = hi
    ws2[(size_t)(i * 32 + 16 + l) * nbatch + batch] = sl[l];   // nib 1 = lo
  }
}

extern "C" __global__ void __launch_bounds__(64, 1)
k2_chain(const float* __restrict__ ws1, float* __restrict__ ws2, int nbatch) {
  const size_t batch = (size_t)blockIdx.x * 64 + threadIdx.x;
  if (batch >= (size_t)nbatch) return;
  // reference quirk: initial carry [1.0] broadcasts to BOTH carry slots
  float cr0 = 1.0f, cr1 = 1.0f;
  float bufA[64], bufB[64];                 // static indexing only (no scratch)
  k2_load(ws1, 0, batch, nbatch, bufA);
  k2_load(ws1, 1, batch, nbatch, bufB);     // prefetch hides under einsum
  k2_step(bufA, cr0, cr1, ws2, 0, batch, nbatch);
  k2_load(ws1, 2, batch, nbatch, bufA);
  k2_step(bufB, cr0, cr1, ws2, 1, batch, nbatch);
  k2_load(ws1, 3, batch, nbatch, bufB);
  k2_step(bufA, cr0, cr1, ws2, 2, batch, nbatch);
  k2_step(bufB, cr0, cr1, ws2, 3, batch, nbatch);
}

// ---------------- K3: double output softmax + outer product -> O ----------------
extern "C" __global__ void __launch_bounds__(256, 1)
k3_out(const float* __restrict__ ws2, float* __restrict__ O, int nbatch) {
  __shared__ float pout[64][36];  // hi probs at 0..15, lo probs at 20..35
  const int tid = threadIdx.x;
  const int batch0 = blockIdx.x * 64;
  const int ib = blockIdx.y;
  if (batch0 >= nbatch) return;

  if (tid < 128) {
    const int nib = tid >> 6, bb = tid & 63;
    float x[16], p[16], p2[16];
#pragma unroll
    for (int l = 0; l < 16; ++l)
      x[l] = ws2[(size_t)(ib * 32 + nib * 16 + l) * nbatch + batch0 + bb];
    softmax16_np(x, p);    // ps (nibble_add's output softmax)
    softmax16_np(p, p2);   // from_nibbles softmax (separable factor)
#pragma unroll
    for (int j = 0; j < 16; ++j) pout[bb][nib * 20 + j] = p2[j];
  }
  __syncthreads();

#pragma unroll
  for (int kk = 0; kk < 16; ++kk) {
    int flat = kk * 1024 + tid * 4;   // 64 batches x 256 bytes
    int bb = flat >> 8;
    int b0 = flat & 255;              // multiple of 4
    float ph = pout[bb][b0 >> 4];
    int lo = 20 + (b0 & 15);
    float4 o;
    o.x = ph * pout[bb][lo + 0];
    o.y = ph * pout[bb][lo + 1];
    o.z = ph * pout[bb][lo + 2];
    o.w = ph * pout[bb][lo + 3];
    *(float4*)(O + ((size_t)(batch0 + bb) * 4 + ib) * 256 + b0) = o;
  }
}

// ---------------- Fallback: known-passing single kernel (R4) ----------------
__device__ __forceinline__ void nibble_add_np_fb(const float* px, const float* py,
                                                 float c0, float c1,
                                                 float* ps, float& n0, float& n1) {
  float s[16];
  nibble_add_raw(px, py, c0, c1, s, n0, n1);
  // note: nibble_add_raw computes carry softmax; now the s softmax:
  softmax16_np(s, ps);
}

__device__ __forceinline__ void buckets_np_fb(const float* __restrict__ row,
                                              float* hi, float* lo) {
#pragma clang fp contract(off)
#pragma unroll
  for (int j = 0; j < 16; ++j) { hi[j] = 0.f; lo[j] = 0.f; }
#pragma unroll
  for (int k4 = 0; k4 < 64; ++k4) {
    float4 x = *(const float4*)(row + k4 * 4);
    const int h = k4 >> 2, l0 = (k4 & 3) * 4;
    hi[h] += x.x;  hi[h] += x.y;  hi[h] += x.z;  hi[h] += x.w;
    lo[l0 + 0] += x.x;
    lo[l0 + 1] += x.y;
    lo[l0 + 2] += x.z;
    lo[l0 + 3] += x.w;
  }
}

extern "C" __global__ void __launch_bounds__(64, 1)
byteadd_fallback(const float* __restrict__ A, const float* __restrict__ Bm,
                 float* __restrict__ O, int nbatch) {
#pragma clang fp contract(off)
  const int b = blockIdx.x * 64 + threadIdx.x;
  if (b >= nbatch) return;
  const float* Ab = A + (size_t)b * 1024;
  const float* Bb = Bm + (size_t)b * 1024;
  float* Ob = O + (size_t)b * 1024;
  float cr0 = 1.0f, cr1 = 1.0f;
#pragma unroll 1
  for (int i = 0; i < 4; ++i) {
    float ah[16], al[16], bh[16], bl[16];
    buckets_np_fb(Ab + i * 256, ah, al);
    buckets_np_fb(Bb + i * 256, bh, bl);
    float pah[16], pal[16], pbh[16], pbl[16];
    softmax16_np(ah, pah);
    softmax16_np(al, pal);
    softmax16_np(bh, pbh);
    softmax16_np(bl, pbl);
    float psl[16], psh[16], d0, d1;
    nibble_add_np_fb(pal, pbl, cr0, cr1, psl, d0, d1);
    nibble_add_np_fb(pah, pbh, d0, d1, psh, cr0, cr1);
    float ph2[16], pl2[16];
    softmax16_np(psh, ph2);
    softmax16_np(psl, pl2);
#pragma unroll
    for (int k4 = 0; k4 < 64; ++k4) {
      const int h = k4 >> 2, l0 = (k4 & 3) * 4;
      const float ph = ph2[h];
      float4 o;
      o.x = ph * pl2[l0 + 0];
      o.y = ph * pl2[l0 + 1];
      o.z = ph * pl2[l0 + 2];
      o.w = ph * pl2[l0 + 3];
      *(float4*)(Ob + i * 256 + k4 * 4) = o;
    }
  }
}

extern "C" void kernel_launch(void* const* d_in, const int* in_sizes, int n_in,
                              void* d_out, int out_size, void* d_ws, size_t ws_size,
                              hipStream_t stream) {
  const float* A = (const float*)d_in[0];
  const float* B = (const float*)d_in[1];
  float* O = (float*)d_out;
  int nbatch = in_sizes[0] / 1024;                       // [B,4,256] -> B
  size_t need = (size_t)384 * nbatch * sizeof(float);    // ws1(256*B) + ws2(128*B)
  if (ws_size >= need && (nbatch & 63) == 0) {
    float* ws1 = (float*)d_ws;
    float* ws2 = ws1 + (size_t)256 * nbatch;
    k1_prep<<<dim3(nbatch / 32, 4, 2), dim3(256), 0, stream>>>(A, B, ws1, nbatch);
    k2_chain<<<dim3(nbatch / 64), dim3(64), 0, stream>>>(ws1, ws2, nbatch);
    k3_out<<<dim3(nbatch / 64, 4), dim3(256), 0, stream>>>(ws2, O, nbatch);
  } else {
    byteadd_fallback<<<dim3((nbatch + 63) / 64), dim3(64), 0, stream>>>(A, B, O, nbatch);
  }
}